// Round 6
// baseline (224.463 us; speedup 1.0000x reference)
//
#include <hip/hip_runtime.h>

// AdjacencyGenerator — round 6.
// Algebra: only layer 2 live; MLP affine -> A3 = W3@W2@W1 (+cfull);
// relu(alpha*v) = alpha*relu(v); both layernorms + final dot collapse to a
// closed form in the scalar t = alpha given 23 per-node sums S[dst].
// Round-6 change (perf only, numerics identical to round 5): k_node was
// latency-serialized at VGPR=124 (load->wait->MFMA chains). Now:
//   __launch_bounds__(256,3) (supply is 3 waves/SIMD anyway -> ~170 VGPR cap),
//   Q+K passes interleaved cb-wise (2 independent MFMA chains sharing A-frags),
//   B-fragment prefetch (cb+1 loads issued before cb's MFMAs), V/VM same.

typedef __attribute__((ext_vector_type(8))) short bf16x8;
typedef __attribute__((ext_vector_type(4))) float f32x4;

__device__ __forceinline__ unsigned short f2bf(float f) {  // RNE
  unsigned int u = __float_as_uint(f);
  unsigned int r = (u + 0x7fffu + ((u >> 16) & 1u)) >> 16;
  return (unsigned short)r;
}
__device__ __forceinline__ float blo(unsigned int u) {
  return __uint_as_float(u << 16);
}
__device__ __forceinline__ float bhi(unsigned int u) {
  return __uint_as_float(u & 0xffff0000u);
}

// ==== setup kernel 1: T = W2@W1 | Wq/Wk/Wv -> bf16 (384 blks) | zero sArr ===
__global__ __launch_bounds__(128) void k_TW(
    const float* __restrict__ W2, const float* __restrict__ W1,
    const float* __restrict__ Wq, const float* __restrict__ Wk,
    const float* __restrict__ Wv, float* __restrict__ T,
    unsigned short* __restrict__ Wqb, unsigned short* __restrict__ Wkb,
    unsigned short* __restrict__ Wvb, float* __restrict__ sArr, int N) {
  const int b = blockIdx.x, t = threadIdx.x;
  if (b < 256) {
    float acc = 0.f;
    for (int k = 0; k < 512; ++k) acc += W2[b * 512 + k] * W1[k * 128 + t];
    T[b * 128 + t] = acc;
  } else if (b < 640) {  // 384 blocks * 128 threads = 3 * 16384 elements
    const int idx = (b - 256) * 128 + t;
    const int m = idx >> 14, i = idx & 16383;
    const float* s = (m == 0) ? Wq : (m == 1) ? Wk : Wv;
    unsigned short* d = (m == 0) ? Wqb : (m == 1) ? Wkb : Wvb;
    d[i] = f2bf(s[i]);
  } else {
    const int i = (b - 640) * 128 + t;
    if (i < N) sArr[i] = 0.f;
  }
}

// ============ setup kernel 2: A3b = bf16(W3@T) | cfull | consts ============
__global__ __launch_bounds__(256) void k_Ac(
    const float* __restrict__ W3, const float* __restrict__ T,
    const float* __restrict__ W2, const float* __restrict__ b1,
    const float* __restrict__ b2, const float* __restrict__ b3,
    const float* __restrict__ g, const float* __restrict__ lb,
    const float* __restrict__ fg, const float* __restrict__ fb,
    const float* __restrict__ wv, unsigned short* __restrict__ A3b,
    float* __restrict__ cfull, float* __restrict__ C) {
  __shared__ float t1[256];
  __shared__ float cf[128];
  const int b = blockIdx.x, t = threadIdx.x;
  if (b < 64) {  // two rows of A3 per block
    const int i = 2 * b + (t >> 7), j = t & 127;
    float acc = 0.f;
    for (int k = 0; k < 256; ++k) acc += W3[i * 256 + k] * T[k * 128 + j];
    A3b[i * 128 + j] = f2bf(acc);
    return;
  }
  // b == 64: cfull = W3@(W2@b1+b2)+b3, then the 9 global consts
  float acc = b2[t];
  for (int c = 0; c < 512; ++c) acc += W2[t * 512 + c] * b1[c];
  t1[t] = acc;
  __syncthreads();
  if (t < 128) {
    float a = b3[t];
    for (int k = 0; k < 256; ++k) a += W3[t * 256 + k] * t1[k];
    cfull[t] = a;
    cf[t] = a;
  }
  __syncthreads();
  if (t < 64) {
    const int l = t;
    const float2 gv = ((const float2*)g)[l];
    const float2 bv = ((const float2*)lb)[l];
    const float2 fgv = ((const float2*)fg)[l];
    const float2 fbv = ((const float2*)fb)[l];
    const float2 wvv = ((const float2*)wv)[l];
    const float P0 = cf[2 * l] + bv.x, P1 = cf[2 * l + 1] + bv.y;
    const float w0 = fgv.x * wvv.x, w1 = fgv.y * wvv.y;
    float s[9];
    s[0] = P0 + P1;
    s[1] = P0 * w0 + P1 * w1;
    s[2] = P0 * P0 + P1 * P1;
    s[3] = gv.x + gv.y;
    s[4] = gv.x * w0 + gv.y * w1;
    s[5] = gv.x * gv.x + gv.y * gv.y;
    s[6] = P0 * gv.x + P1 * gv.y;
    s[7] = w0 + w1;
    s[8] = fbv.x * wvv.x + fbv.y * wvv.y;
#pragma unroll
    for (int m = 32; m >= 1; m >>= 1)
#pragma unroll
      for (int i = 0; i < 9; ++i) s[i] += __shfl_xor(s[i], m, 64);
    if (l == 0)
#pragma unroll
      for (int i = 0; i < 9; ++i) C[i] = s[i];
  }
}

// ============ fused node kernel: Q,K tables + fp32 23-scalar collapse =======
// Block 256 = 4 waves over a 64-node tile; wave w owns rows [16w,16w+16).
// MFMA 16x16x32 bf16: A-frag lane l -> X[m=l&15][k=32kb+8*(l>>4)+i];
// B-frag lane l -> W[n][same k]; C/D: row=(l>>4)*4+r, col=l&15 (+16cb).
__global__ __launch_bounds__(256, 3) void k_node(
    const float* __restrict__ x, const unsigned short* __restrict__ Wqb,
    const unsigned short* __restrict__ Wkb,
    const unsigned short* __restrict__ Wvb,
    const unsigned short* __restrict__ A3b, const float* __restrict__ bq,
    const float* __restrict__ bk, const float* __restrict__ bv,
    const float* __restrict__ cfull, const float* __restrict__ g,
    const float* __restrict__ lb, const float* __restrict__ fg,
    const float* __restrict__ wvp, unsigned short* __restrict__ Qb,
    unsigned short* __restrict__ Kb, float* __restrict__ S, int N) {
  __shared__ float xf[64][132];            // fp32 x tile
  __shared__ unsigned short uls[64][136];  // bf16 U (VM MFMA input only)
  __shared__ float cg[128], cw[128], cP[128];
  const int t = threadIdx.x;
  const int nb = blockIdx.x * 64;
  if (t < 128) {
    cg[t] = g[t];
    cw[t] = fg[t] * wvp[t];
    cP[t] = cfull[t] + lb[t];
  }
  // stage x -> fp32 LDS
  for (int i = t; i < 64 * 32; i += 256) {
    const int j = i >> 5, c4 = i & 31;
    const int n = nb + j;
    float4 v = make_float4(0.f, 0.f, 0.f, 0.f);
    if (n < N) v = ((const float4*)x)[(size_t)n * 32 + c4];
    *(float4*)&xf[j][c4 * 4] = v;
  }
  __syncthreads();
  const int wv16 = __builtin_amdgcn_readfirstlane(t >> 6) * 16;
  const int l = t & 63;
  const int ln = l & 15, g4 = l >> 4;

  // A-frags: convert fp32 LDS -> bf16 on the fly
  bf16x8 af[4];
#pragma unroll
  for (int kb = 0; kb < 4; ++kb) {
    const float* p = &xf[wv16 + ln][kb * 32 + g4 * 8];
    const float4 a0 = *(const float4*)p;
    const float4 a1 = *(const float4*)(p + 4);
    bf16x8 r;
    r[0] = (short)f2bf(a0.x); r[1] = (short)f2bf(a0.y);
    r[2] = (short)f2bf(a0.z); r[3] = (short)f2bf(a0.w);
    r[4] = (short)f2bf(a1.x); r[5] = (short)f2bf(a1.y);
    r[6] = (short)f2bf(a1.z); r[7] = (short)f2bf(a1.w);
    af[kb] = r;
  }

  // ---- Q+K passes interleaved, with cb+1 B-frag prefetch ----
  {
    bf16x8 qf[4], kf[4];
#pragma unroll
    for (int kb = 0; kb < 4; ++kb) {
      qf[kb] = *(const bf16x8*)(Wqb + (ln << 7) + kb * 32 + g4 * 8);
      kf[kb] = *(const bf16x8*)(Wkb + (ln << 7) + kb * 32 + g4 * 8);
    }
#pragma unroll
    for (int cb = 0; cb < 8; ++cb) {
      bf16x8 qn[4], kn[4];
      if (cb < 7) {
#pragma unroll
        for (int kb = 0; kb < 4; ++kb) {
          const int off = (((cb + 1) * 16 + ln) << 7) + kb * 32 + g4 * 8;
          qn[kb] = *(const bf16x8*)(Wqb + off);
          kn[kb] = *(const bf16x8*)(Wkb + off);
        }
      }
      f32x4 qa = {0.f, 0.f, 0.f, 0.f}, ka = {0.f, 0.f, 0.f, 0.f};
#pragma unroll
      for (int kb = 0; kb < 4; ++kb) {
        qa = __builtin_amdgcn_mfma_f32_16x16x32_bf16(af[kb], qf[kb], qa, 0, 0, 0);
        ka = __builtin_amdgcn_mfma_f32_16x16x32_bf16(af[kb], kf[kb], ka, 0, 0, 0);
      }
      const int col = cb * 16 + ln;
      const float bqc = bq[col], bkc = bk[col];
#pragma unroll
      for (int r = 0; r < 4; ++r) {
        const int n = nb + wv16 + g4 * 4 + r;
        if (n < N) {
          Qb[(size_t)n * 128 + col] = f2bf(qa[r] + bqc);
          Kb[(size_t)n * 128 + col] = f2bf(ka[r] + bkc);
        }
      }
#pragma unroll
      for (int kb = 0; kb < 4; ++kb) {
        qf[kb] = qn[kb];
        kf[kb] = kn[kb];
      }
    }
  }

  // ---- V pass (prefetched): uf fp32 regs (exact) + bf16 copy to LDS ----
  float uf[8][4];
  {
    bf16x8 vf[4];
#pragma unroll
    for (int kb = 0; kb < 4; ++kb)
      vf[kb] = *(const bf16x8*)(Wvb + (ln << 7) + kb * 32 + g4 * 8);
#pragma unroll
    for (int cb = 0; cb < 8; ++cb) {
      bf16x8 vn[4];
      if (cb < 7) {
#pragma unroll
        for (int kb = 0; kb < 4; ++kb)
          vn[kb] = *(const bf16x8*)(Wvb + (((cb + 1) * 16 + ln) << 7) +
                                    kb * 32 + g4 * 8);
      }
      f32x4 acc = {0.f, 0.f, 0.f, 0.f};
#pragma unroll
      for (int kb = 0; kb < 4; ++kb)
        acc = __builtin_amdgcn_mfma_f32_16x16x32_bf16(af[kb], vf[kb], acc, 0, 0, 0);
      const int col = cb * 16 + ln;
      const float bs = bv[col];
#pragma unroll
      for (int r = 0; r < 4; ++r) {
        const float v = fmaxf(acc[r] + bs, 0.f);
        uf[cb][r] = v;
        uls[wv16 + g4 * 4 + r][col] = f2bf(v);
      }
#pragma unroll
      for (int kb = 0; kb < 4; ++kb) vf[kb] = vn[kb];
    }
  }

  // ---- VM pass (same-wave rows -> no barrier): vmf fp32 regs (exact) ----
  bf16x8 af2[4];
#pragma unroll
  for (int kb = 0; kb < 4; ++kb)
    af2[kb] = *(const bf16x8*)&uls[wv16 + ln][kb * 32 + g4 * 8];
  float vmf[8][4];
  {
    bf16x8 mf[4];
#pragma unroll
    for (int kb = 0; kb < 4; ++kb)
      mf[kb] = *(const bf16x8*)(A3b + (ln << 7) + kb * 32 + g4 * 8);
#pragma unroll
    for (int cb = 0; cb < 8; ++cb) {
      bf16x8 mn[4];
      if (cb < 7) {
#pragma unroll
        for (int kb = 0; kb < 4; ++kb)
          mn[kb] = *(const bf16x8*)(A3b + (((cb + 1) * 16 + ln) << 7) +
                                    kb * 32 + g4 * 8);
      }
      f32x4 acc = {0.f, 0.f, 0.f, 0.f};
#pragma unroll
      for (int kb = 0; kb < 4; ++kb)
        acc = __builtin_amdgcn_mfma_f32_16x16x32_bf16(af2[kb], mf[kb], acc, 0, 0, 0);
#pragma unroll
      for (int r = 0; r < 4; ++r) vmf[cb][r] = acc[r];
#pragma unroll
      for (int kb = 0; kb < 4; ++kb) mf[kb] = mn[kb];
    }
  }

  // hoist fp32 consts at this lane's 8 columns
  float gc[8], wc[8], Pc[8];
#pragma unroll
  for (int cb = 0; cb < 8; ++cb) {
    const int col = cb * 16 + ln;
    gc[cb] = cg[col];
    wc[cb] = cw[col];
    Pc[cb] = cP[col];
  }

  // ---- 23-scalar collapse, all fp32 (round-2 numerics) ----
#pragma unroll
  for (int r = 0; r < 4; ++r) {
    const int row = wv16 + g4 * 4 + r;
    float s[23];
#pragma unroll
    for (int i = 0; i < 23; ++i) s[i] = 0.f;
#pragma unroll
    for (int cb = 0; cb < 8; ++cb) {
      const float xv = xf[row][cb * 16 + ln];
      const float u = uf[cb][r];
      const float v = vmf[cb][r];
      const float gg = gc[cb], ww = wc[cb], PP = Pc[cb];
      const float xg = xv * gg, ug = u * gg;
      s[0] += xv;
      s[1] += u;
      s[2] += xv * xv;
      s[3] += xv * u;
      s[4] += u * u;
      s[5] += v;
      s[6] += v * ww;
      s[7] += xg;
      s[8] += ug;
      s[9] += xg * ww;
      s[10] += ug * ww;
      s[11] += PP * v;
      s[12] += v * v;
      s[13] += PP * xg;
      s[14] += PP * ug;
      s[15] += v * xg;
      s[16] += v * ug;
      s[17] += v * gg;
      s[18] += xg * xg;
      s[19] += xg * ug;
      s[20] += ug * ug;
      s[21] += xg * gg;
      s[22] += ug * gg;
    }
#pragma unroll
    for (int m = 1; m <= 8; m <<= 1)
#pragma unroll
      for (int i = 0; i < 23; ++i) s[i] += __shfl_xor(s[i], m, 64);
    const int n2 = nb + row;
    if (ln == 0 && n2 < N) {
      float* o = S + (size_t)n2 * 24;
      o[0] = s[0] * (1.f / 128.f);
      o[1] = s[1] * (1.f / 128.f);
#pragma unroll
      for (int i = 2; i < 23; ++i) o[i] = s[i];
      o[23] = 0.f;
    }
  }
}

// ============ edge pass 1: alpha + segment sum ============
__global__ __launch_bounds__(256) void k_edge_alpha(
    const int* __restrict__ ei, const unsigned short* __restrict__ Qb,
    const unsigned short* __restrict__ Kb, float* __restrict__ eArr,
    float* __restrict__ sArr, int E) {
  const int t = threadIdx.x;
  const int l = t & 15;
  const int e = blockIdx.x * 16 + (t >> 4);
  if (e >= E) return;
  const int src = ei[e];
  const int dst = ei[E + e];
  const uint4 qv = ((const uint4*)Qb)[(size_t)src * 16 + l];
  const uint4 kv = ((const uint4*)Kb)[(size_t)dst * 16 + l];
  float p = blo(qv.x) * blo(kv.x);
  p = fmaf(bhi(qv.x), bhi(kv.x), p);
  p = fmaf(blo(qv.y), blo(kv.y), p);
  p = fmaf(bhi(qv.y), bhi(kv.y), p);
  p = fmaf(blo(qv.z), blo(kv.z), p);
  p = fmaf(bhi(qv.z), bhi(kv.z), p);
  p = fmaf(blo(qv.w), blo(kv.w), p);
  p = fmaf(bhi(qv.w), bhi(kv.w), p);
#pragma unroll
  for (int m = 8; m >= 1; m >>= 1) p += __shfl_xor(p, m, 16);
  if (l == 0) {
    const float ex = __expf(p);  // max-shift dropped: exactly equivalent
    eArr[e] = ex;
    atomicAdd(&sArr[dst], ex);
  }
}

// ============ edge pass 2: closed-form logit ============
__global__ __launch_bounds__(256) void k_edge_out(
    const int* __restrict__ ei, const float* __restrict__ eArr,
    const float* __restrict__ sArr, const float* __restrict__ S,
    const float* __restrict__ C, const float* __restrict__ bvec,
    float* __restrict__ out, int E) {
  const int e = blockIdx.x * 256 + threadIdx.x;
  if (e >= E) return;
  const int dst = ei[E + e];
  const float t = eArr[e] / (sArr[dst] + 1e-16f);
  const float4* o = (const float4*)(S + (size_t)dst * 24);
  const float4 q0 = o[0], q1 = o[1], q2 = o[2], q3 = o[3], q4 = o[4],
               q5 = o[5];
  const float mx = q0.x, mU = q0.y, sxx = q0.z, sxu = q0.w;
  const float suu = q1.x, sv = q1.y, svw = q1.z, sxg = q1.w;
  const float sug = q2.x, sxgw = q2.y, sugw = q2.z, spv = q2.w;
  const float svv = q3.x, pxg = q3.y, pug = q3.z, vxg = q3.w;
  const float vug = q4.x, vg = q4.y, xgxg = q4.z, xgug = q4.w;
  const float ugug = q5.x, xgg = q5.y, ugg = q5.z;
  const float SP = C[0], SPw = C[1], SPP = C[2], SG = C[3], SGw = C[4],
              GG = C[5], SPG = C[6], Sw = C[7], s0 = C[8];
  const float mu = mx + t * mU;
  const float qy = (sxx + 2.f * t * sxu + t * t * suu) * (1.f / 128.f);
  const float i1 = rsqrtf(qy - mu * mu + 1e-5f);
  const float sz = SP + t * sv + i1 * (sxg + t * sug - mu * SG);
  const float szw = SPw + t * svw + i1 * (sxgw + t * sugw - mu * SGw);
  const float cross = pxg + t * (pug + vxg) + t * t * vug - mu * (SPG + t * vg);
  const float rr = xgxg + 2.f * t * xgug + t * t * ugug -
                   2.f * mu * (xgg + t * ugg) + mu * mu * GG;
  const float szz =
      SPP + 2.f * t * spv + t * t * svv + 2.f * i1 * cross + i1 * i1 * rr;
  const float muz = sz * (1.f / 128.f);
  const float varz = szz * (1.f / 128.f) - muz * muz;
  const float iz = rsqrtf(varz + 1e-5f);
  out[e] = iz * (szw - muz * Sw) + s0 + bvec[0];
}

extern "C" void kernel_launch(void* const* d_in, const int* in_sizes, int n_in,
                              void* d_out, int out_size, void* d_ws,
                              size_t ws_size, hipStream_t stream) {
  const int* ei = (const int*)d_in[0];
  const float* x = (const float*)d_in[1];
  const float* Wq = (const float*)d_in[2];
  const float* bq = (const float*)d_in[3];
  const float* Wk = (const float*)d_in[4];
  const float* bk = (const float*)d_in[5];
  const float* Wv = (const float*)d_in[6];
  const float* bv = (const float*)d_in[7];
  const float* ln_g = (const float*)d_in[8];
  const float* ln_b = (const float*)d_in[9];
  const float* W1 = (const float*)d_in[10];
  const float* b1 = (const float*)d_in[11];
  const float* W2 = (const float*)d_in[12];
  const float* b2 = (const float*)d_in[13];
  const float* W3 = (const float*)d_in[14];
  const float* b3 = (const float*)d_in[15];
  const float* Wvec = (const float*)d_in[16];
  const float* bvec = (const float*)d_in[17];
  const float* fn_g = (const float*)d_in[18];
  const float* fn_b = (const float*)d_in[19];

  const int E = in_sizes[0] / 2;
  const int N = in_sizes[1] / 128;

  // only layer 2 is live
  const float* Wq2 = Wq + 2 * 128 * 128;
  const float* bq2 = bq + 2 * 128;
  const float* Wk2 = Wk + 2 * 128 * 128;
  const float* bk2 = bk + 2 * 128;
  const float* Wv2 = Wv + 2 * 128 * 128;
  const float* bv2 = bv + 2 * 128;
  const float* g2 = ln_g + 2 * 128;
  const float* lb2 = ln_b + 2 * 128;

  float* ws = (float*)d_ws;
  float* T = ws;                 // 32768
  float* cfull = T + 32768;      // 128
  float* consts = cfull + 128;   // 16
  unsigned short* Wqb = (unsigned short*)(consts + 16);  // 16384 us each
  unsigned short* Wkb = Wqb + 16384;
  unsigned short* Wvb = Wkb + 16384;
  unsigned short* A3b = Wvb + 16384;
  float* fbase = consts + 16 + 32768;  // after 4*16384 bf16 = 32768 floats
  unsigned short* Qb = (unsigned short*)fbase;  // N*128 bf16
  unsigned short* Kb = Qb + (size_t)N * 128;
  float* S = fbase + (size_t)N * 128;  // N*24 (after Qb+Kb)
  float* eArr = S + (size_t)N * 24;    // E
  float* sArr = eArr + E;              // N

  const int zblk = (N + 127) / 128;
  k_TW<<<640 + zblk, 128, 0, stream>>>(W2, W1, Wq2, Wk2, Wv2, T, Wqb, Wkb,
                                       Wvb, sArr, N);
  k_Ac<<<65, 256, 0, stream>>>(W3, T, W2, b1, b2, b3, g2, lb2, fn_g, fn_b,
                               Wvec, A3b, cfull, consts);

  const int nblk = (N + 63) / 64;
  k_node<<<nblk, 256, 0, stream>>>(x, Wqb, Wkb, Wvb, A3b, bq2, bk2, bv2,
                                   cfull, g2, lb2, fn_g, Wvec, Qb, Kb, S, N);
  const int ablk = (E + 15) / 16;
  k_edge_alpha<<<ablk, 256, 0, stream>>>(ei, Qb, Kb, eArr, sArr, E);
  const int oblk = (E + 255) / 256;
  k_edge_out<<<oblk, 256, 0, stream>>>(ei, eArr, sArr, S, consts, bvec,
                                       (float*)d_out, E);
}

// Round 7
// 221.872 us; speedup vs baseline: 1.0117x; 1.0117x over previous
//
#include <hip/hip_runtime.h>

// AdjacencyGenerator — round 7.
// Algebra: only layer 2 live; MLP affine -> A3 = W3@W2@W1 (+cfull);
// relu(alpha*v) = alpha*relu(v); both layernorms + final dot collapse to a
// closed form in the scalar t = alpha given 23 per-node sums S[dst].
// Round-7 theory: k_node's ~90us across r2/r5/r6 is stall from scattered
// 2-byte global stores (partial-line RFO/eviction: r6 FETCH ~= sizeof(Qb+Kb),
// WRITE 2x). Fix: write results to the one reused LDS tile, store full
// 256B rows coalesced (b128/lane). Stats read exact fp32 x from global
// (L2-hot); LDS 52.7KB -> 17.4KB; numerics identical to round 5.

typedef __attribute__((ext_vector_type(8))) short bf16x8;
typedef __attribute__((ext_vector_type(4))) float f32x4;

__device__ __forceinline__ unsigned short f2bf(float f) {  // RNE
  unsigned int u = __float_as_uint(f);
  unsigned int r = (u + 0x7fffu + ((u >> 16) & 1u)) >> 16;
  return (unsigned short)r;
}
__device__ __forceinline__ float blo(unsigned int u) {
  return __uint_as_float(u << 16);
}
__device__ __forceinline__ float bhi(unsigned int u) {
  return __uint_as_float(u & 0xffff0000u);
}

// ==== setup kernel 1: T = W2@W1 | Wq/Wk/Wv -> bf16 (384 blks) | zero sArr ===
__global__ __launch_bounds__(128) void k_TW(
    const float* __restrict__ W2, const float* __restrict__ W1,
    const float* __restrict__ Wq, const float* __restrict__ Wk,
    const float* __restrict__ Wv, float* __restrict__ T,
    unsigned short* __restrict__ Wqb, unsigned short* __restrict__ Wkb,
    unsigned short* __restrict__ Wvb, float* __restrict__ sArr, int N) {
  const int b = blockIdx.x, t = threadIdx.x;
  if (b < 256) {
    float acc = 0.f;
    for (int k = 0; k < 512; ++k) acc += W2[b * 512 + k] * W1[k * 128 + t];
    T[b * 128 + t] = acc;
  } else if (b < 640) {  // 384 blocks * 128 threads = 3 * 16384 elements
    const int idx = (b - 256) * 128 + t;
    const int m = idx >> 14, i = idx & 16383;
    const float* s = (m == 0) ? Wq : (m == 1) ? Wk : Wv;
    unsigned short* d = (m == 0) ? Wqb : (m == 1) ? Wkb : Wvb;
    d[i] = f2bf(s[i]);
  } else {
    const int i = (b - 640) * 128 + t;
    if (i < N) sArr[i] = 0.f;
  }
}

// ============ setup kernel 2: A3b = bf16(W3@T) | cfull | consts ============
__global__ __launch_bounds__(256) void k_Ac(
    const float* __restrict__ W3, const float* __restrict__ T,
    const float* __restrict__ W2, const float* __restrict__ b1,
    const float* __restrict__ b2, const float* __restrict__ b3,
    const float* __restrict__ g, const float* __restrict__ lb,
    const float* __restrict__ fg, const float* __restrict__ fb,
    const float* __restrict__ wv, unsigned short* __restrict__ A3b,
    float* __restrict__ cfull, float* __restrict__ C) {
  __shared__ float t1[256];
  __shared__ float cf[128];
  const int b = blockIdx.x, t = threadIdx.x;
  if (b < 64) {  // two rows of A3 per block
    const int i = 2 * b + (t >> 7), j = t & 127;
    float acc = 0.f;
    for (int k = 0; k < 256; ++k) acc += W3[i * 256 + k] * T[k * 128 + j];
    A3b[i * 128 + j] = f2bf(acc);
    return;
  }
  // b == 64: cfull = W3@(W2@b1+b2)+b3, then the 9 global consts
  float acc = b2[t];
  for (int c = 0; c < 512; ++c) acc += W2[t * 512 + c] * b1[c];
  t1[t] = acc;
  __syncthreads();
  if (t < 128) {
    float a = b3[t];
    for (int k = 0; k < 256; ++k) a += W3[t * 256 + k] * t1[k];
    cfull[t] = a;
    cf[t] = a;
  }
  __syncthreads();
  if (t < 64) {
    const int l = t;
    const float2 gv = ((const float2*)g)[l];
    const float2 bv = ((const float2*)lb)[l];
    const float2 fgv = ((const float2*)fg)[l];
    const float2 fbv = ((const float2*)fb)[l];
    const float2 wvv = ((const float2*)wv)[l];
    const float P0 = cf[2 * l] + bv.x, P1 = cf[2 * l + 1] + bv.y;
    const float w0 = fgv.x * wvv.x, w1 = fgv.y * wvv.y;
    float s[9];
    s[0] = P0 + P1;
    s[1] = P0 * w0 + P1 * w1;
    s[2] = P0 * P0 + P1 * P1;
    s[3] = gv.x + gv.y;
    s[4] = gv.x * w0 + gv.y * w1;
    s[5] = gv.x * gv.x + gv.y * gv.y;
    s[6] = P0 * gv.x + P1 * gv.y;
    s[7] = w0 + w1;
    s[8] = fbv.x * wvv.x + fbv.y * wvv.y;
#pragma unroll
    for (int m = 32; m >= 1; m >>= 1)
#pragma unroll
      for (int i = 0; i < 9; ++i) s[i] += __shfl_xor(s[i], m, 64);
    if (l == 0)
#pragma unroll
      for (int i = 0; i < 9; ++i) C[i] = s[i];
  }
}

// ============ fused node kernel: Q,K tables + fp32 23-scalar collapse =======
// Block 256 = 4 waves over a 64-node tile; wave w owns rows [16w,16w+16).
// One LDS tile, reused per pass: compute -> bf16 tile -> coalesced b128
// row stores (full 256B lines; no scattered 2B global stores).
// MFMA 16x16x32 bf16: A-frag lane l -> X[m=l&15][k=32kb+8*(l>>4)+i];
// C/D: row=(l>>4)*4+r, col=l&15 (+16cb).
__global__ __launch_bounds__(256, 3) void k_node(
    const float* __restrict__ x, const unsigned short* __restrict__ Wqb,
    const unsigned short* __restrict__ Wkb,
    const unsigned short* __restrict__ Wvb,
    const unsigned short* __restrict__ A3b, const float* __restrict__ bq,
    const float* __restrict__ bk, const float* __restrict__ bv,
    const float* __restrict__ cfull, const float* __restrict__ g,
    const float* __restrict__ lb, const float* __restrict__ fg,
    const float* __restrict__ wvp, unsigned short* __restrict__ Qb,
    unsigned short* __restrict__ Kb, float* __restrict__ S, int N) {
  __shared__ unsigned short tile[64][136];
  const int t = threadIdx.x;
  const int nb = blockIdx.x * 64;
  // stage x -> bf16 tile (coalesced float4 loads); MFMA input only
  for (int i = t; i < 64 * 32; i += 256) {
    const int j = i >> 5, c4 = i & 31;
    const int n = nb + j;
    float4 v = make_float4(0.f, 0.f, 0.f, 0.f);
    if (n < N) v = ((const float4*)x)[(size_t)n * 32 + c4];
    unsigned int lo = f2bf(v.x) | ((unsigned int)f2bf(v.y) << 16);
    unsigned int hi = f2bf(v.z) | ((unsigned int)f2bf(v.w) << 16);
    *(uint2*)&tile[j][c4 << 2] = make_uint2(lo, hi);
  }
  __syncthreads();
  const int wv16 = __builtin_amdgcn_readfirstlane(t >> 6) * 16;
  const int l = t & 63;
  const int ln = l & 15, g4 = l >> 4;
  bf16x8 af[4];
#pragma unroll
  for (int kb = 0; kb < 4; ++kb)
    af[kb] = *(const bf16x8*)&tile[wv16 + ln][kb * 32 + g4 * 8];
  // From here on, tile rows [wv16,wv16+16) are touched only by this wave:
  // no further barriers needed.

  // ---- Q pass: MFMA -> bf16 tile -> coalesced row store ----
#pragma unroll
  for (int cb = 0; cb < 8; ++cb) {
    f32x4 acc = {0.f, 0.f, 0.f, 0.f};
#pragma unroll
    for (int kb = 0; kb < 4; ++kb) {
      const bf16x8 bfr =
          *(const bf16x8*)(Wqb + ((cb * 16 + ln) << 7) + kb * 32 + g4 * 8);
      acc = __builtin_amdgcn_mfma_f32_16x16x32_bf16(af[kb], bfr, acc, 0, 0, 0);
    }
    const int col = cb * 16 + ln;
    const float bs = bq[col];
#pragma unroll
    for (int r = 0; r < 4; ++r) tile[wv16 + g4 * 4 + r][col] = f2bf(acc[r] + bs);
  }
#pragma unroll
  for (int c = 0; c < 4; ++c) {
    const int row = wv16 + c * 4 + g4;
    const int n = nb + row;
    if (n < N)
      ((uint4*)(Qb + (size_t)n * 128))[ln] = *(const uint4*)&tile[row][ln * 8];
  }

  // ---- K pass ----
#pragma unroll
  for (int cb = 0; cb < 8; ++cb) {
    f32x4 acc = {0.f, 0.f, 0.f, 0.f};
#pragma unroll
    for (int kb = 0; kb < 4; ++kb) {
      const bf16x8 bfr =
          *(const bf16x8*)(Wkb + ((cb * 16 + ln) << 7) + kb * 32 + g4 * 8);
      acc = __builtin_amdgcn_mfma_f32_16x16x32_bf16(af[kb], bfr, acc, 0, 0, 0);
    }
    const int col = cb * 16 + ln;
    const float bs = bk[col];
#pragma unroll
    for (int r = 0; r < 4; ++r) tile[wv16 + g4 * 4 + r][col] = f2bf(acc[r] + bs);
  }
#pragma unroll
  for (int c = 0; c < 4; ++c) {
    const int row = wv16 + c * 4 + g4;
    const int n = nb + row;
    if (n < N)
      ((uint4*)(Kb + (size_t)n * 128))[ln] = *(const uint4*)&tile[row][ln * 8];
  }

  // ---- V pass: uf fp32 regs (exact) + bf16 tile (VM MFMA input) ----
  float uf[8][4];
#pragma unroll
  for (int cb = 0; cb < 8; ++cb) {
    f32x4 acc = {0.f, 0.f, 0.f, 0.f};
#pragma unroll
    for (int kb = 0; kb < 4; ++kb) {
      const bf16x8 bfr =
          *(const bf16x8*)(Wvb + ((cb * 16 + ln) << 7) + kb * 32 + g4 * 8);
      acc = __builtin_amdgcn_mfma_f32_16x16x32_bf16(af[kb], bfr, acc, 0, 0, 0);
    }
    const int col = cb * 16 + ln;
    const float bs = bv[col];
#pragma unroll
    for (int r = 0; r < 4; ++r) {
      const float v = fmaxf(acc[r] + bs, 0.f);
      uf[cb][r] = v;
      tile[wv16 + g4 * 4 + r][col] = f2bf(v);
    }
  }

  // ---- VM pass (own rows; no barrier): vmf fp32 regs (exact) ----
  bf16x8 af2[4];
#pragma unroll
  for (int kb = 0; kb < 4; ++kb)
    af2[kb] = *(const bf16x8*)&tile[wv16 + ln][kb * 32 + g4 * 8];
  float vmf[8][4];
#pragma unroll
  for (int cb = 0; cb < 8; ++cb) {
    f32x4 acc = {0.f, 0.f, 0.f, 0.f};
#pragma unroll
    for (int kb = 0; kb < 4; ++kb) {
      const bf16x8 bfr =
          *(const bf16x8*)(A3b + ((cb * 16 + ln) << 7) + kb * 32 + g4 * 8);
      acc = __builtin_amdgcn_mfma_f32_16x16x32_bf16(af2[kb], bfr, acc, 0, 0, 0);
    }
#pragma unroll
    for (int r = 0; r < 4; ++r) vmf[cb][r] = acc[r];
  }

  // consts at this lane's 8 columns (L2-broadcast loads; no LDS)
  float gc[8], wc[8], Pc[8];
#pragma unroll
  for (int cb = 0; cb < 8; ++cb) {
    const int col = cb * 16 + ln;
    gc[cb] = g[col];
    wc[cb] = fg[col] * wvp[col];
    Pc[cb] = cfull[col] + lb[col];
  }

  // ---- 23-scalar collapse, all fp32 (round-5 numerics; x re-read fp32) ----
#pragma unroll
  for (int r = 0; r < 4; ++r) {
    const int row = wv16 + g4 * 4 + r;
    const int nrow = (nb + row < N) ? (nb + row) : (N - 1);  // clamp OOB
    float s[23];
#pragma unroll
    for (int i = 0; i < 23; ++i) s[i] = 0.f;
#pragma unroll
    for (int cb = 0; cb < 8; ++cb) {
      const float xv = x[(size_t)nrow * 128 + cb * 16 + ln];
      const float u = uf[cb][r];
      const float v = vmf[cb][r];
      const float gg = gc[cb], ww = wc[cb], PP = Pc[cb];
      const float xg = xv * gg, ug = u * gg;
      s[0] += xv;
      s[1] += u;
      s[2] += xv * xv;
      s[3] += xv * u;
      s[4] += u * u;
      s[5] += v;
      s[6] += v * ww;
      s[7] += xg;
      s[8] += ug;
      s[9] += xg * ww;
      s[10] += ug * ww;
      s[11] += PP * v;
      s[12] += v * v;
      s[13] += PP * xg;
      s[14] += PP * ug;
      s[15] += v * xg;
      s[16] += v * ug;
      s[17] += v * gg;
      s[18] += xg * xg;
      s[19] += xg * ug;
      s[20] += ug * ug;
      s[21] += xg * gg;
      s[22] += ug * gg;
    }
#pragma unroll
    for (int m = 1; m <= 8; m <<= 1)
#pragma unroll
      for (int i = 0; i < 23; ++i) s[i] += __shfl_xor(s[i], m, 64);
    const int n2 = nb + row;
    if (ln == 0 && n2 < N) {
      float* o = S + (size_t)n2 * 24;
      o[0] = s[0] * (1.f / 128.f);
      o[1] = s[1] * (1.f / 128.f);
#pragma unroll
      for (int i = 2; i < 23; ++i) o[i] = s[i];
      o[23] = 0.f;
    }
  }
}

// ============ edge pass 1: alpha + segment sum ============
__global__ __launch_bounds__(256) void k_edge_alpha(
    const int* __restrict__ ei, const unsigned short* __restrict__ Qb,
    const unsigned short* __restrict__ Kb, float* __restrict__ eArr,
    float* __restrict__ sArr, int E) {
  const int t = threadIdx.x;
  const int l = t & 15;
  const int e = blockIdx.x * 16 + (t >> 4);
  if (e >= E) return;
  const int src = ei[e];
  const int dst = ei[E + e];
  const uint4 qv = ((const uint4*)Qb)[(size_t)src * 16 + l];
  const uint4 kv = ((const uint4*)Kb)[(size_t)dst * 16 + l];
  float p = blo(qv.x) * blo(kv.x);
  p = fmaf(bhi(qv.x), bhi(kv.x), p);
  p = fmaf(blo(qv.y), blo(kv.y), p);
  p = fmaf(bhi(qv.y), bhi(kv.y), p);
  p = fmaf(blo(qv.z), blo(kv.z), p);
  p = fmaf(bhi(qv.z), bhi(kv.z), p);
  p = fmaf(blo(qv.w), blo(kv.w), p);
  p = fmaf(bhi(qv.w), bhi(kv.w), p);
#pragma unroll
  for (int m = 8; m >= 1; m >>= 1) p += __shfl_xor(p, m, 16);
  if (l == 0) {
    const float ex = __expf(p);  // max-shift dropped: exactly equivalent
    eArr[e] = ex;
    atomicAdd(&sArr[dst], ex);
  }
}

// ============ edge pass 2: closed-form logit ============
__global__ __launch_bounds__(256) void k_edge_out(
    const int* __restrict__ ei, const float* __restrict__ eArr,
    const float* __restrict__ sArr, const float* __restrict__ S,
    const float* __restrict__ C, const float* __restrict__ bvec,
    float* __restrict__ out, int E) {
  const int e = blockIdx.x * 256 + threadIdx.x;
  if (e >= E) return;
  const int dst = ei[E + e];
  const float t = eArr[e] / (sArr[dst] + 1e-16f);
  const float4* o = (const float4*)(S + (size_t)dst * 24);
  const float4 q0 = o[0], q1 = o[1], q2 = o[2], q3 = o[3], q4 = o[4],
               q5 = o[5];
  const float mx = q0.x, mU = q0.y, sxx = q0.z, sxu = q0.w;
  const float suu = q1.x, sv = q1.y, svw = q1.z, sxg = q1.w;
  const float sug = q2.x, sxgw = q2.y, sugw = q2.z, spv = q2.w;
  const float svv = q3.x, pxg = q3.y, pug = q3.z, vxg = q3.w;
  const float vug = q4.x, vg = q4.y, xgxg = q4.z, xgug = q4.w;
  const float ugug = q5.x, xgg = q5.y, ugg = q5.z;
  const float SP = C[0], SPw = C[1], SPP = C[2], SG = C[3], SGw = C[4],
              GG = C[5], SPG = C[6], Sw = C[7], s0 = C[8];
  const float mu = mx + t * mU;
  const float qy = (sxx + 2.f * t * sxu + t * t * suu) * (1.f / 128.f);
  const float i1 = rsqrtf(qy - mu * mu + 1e-5f);
  const float sz = SP + t * sv + i1 * (sxg + t * sug - mu * SG);
  const float szw = SPw + t * svw + i1 * (sxgw + t * sugw - mu * SGw);
  const float cross = pxg + t * (pug + vxg) + t * t * vug - mu * (SPG + t * vg);
  const float rr = xgxg + 2.f * t * xgug + t * t * ugug -
                   2.f * mu * (xgg + t * ugg) + mu * mu * GG;
  const float szz =
      SPP + 2.f * t * spv + t * t * svv + 2.f * i1 * cross + i1 * i1 * rr;
  const float muz = sz * (1.f / 128.f);
  const float varz = szz * (1.f / 128.f) - muz * muz;
  const float iz = rsqrtf(varz + 1e-5f);
  out[e] = iz * (szw - muz * Sw) + s0 + bvec[0];
}

extern "C" void kernel_launch(void* const* d_in, const int* in_sizes, int n_in,
                              void* d_out, int out_size, void* d_ws,
                              size_t ws_size, hipStream_t stream) {
  const int* ei = (const int*)d_in[0];
  const float* x = (const float*)d_in[1];
  const float* Wq = (const float*)d_in[2];
  const float* bq = (const float*)d_in[3];
  const float* Wk = (const float*)d_in[4];
  const float* bk = (const float*)d_in[5];
  const float* Wv = (const float*)d_in[6];
  const float* bv = (const float*)d_in[7];
  const float* ln_g = (const float*)d_in[8];
  const float* ln_b = (const float*)d_in[9];
  const float* W1 = (const float*)d_in[10];
  const float* b1 = (const float*)d_in[11];
  const float* W2 = (const float*)d_in[12];
  const float* b2 = (const float*)d_in[13];
  const float* W3 = (const float*)d_in[14];
  const float* b3 = (const float*)d_in[15];
  const float* Wvec = (const float*)d_in[16];
  const float* bvec = (const float*)d_in[17];
  const float* fn_g = (const float*)d_in[18];
  const float* fn_b = (const float*)d_in[19];

  const int E = in_sizes[0] / 2;
  const int N = in_sizes[1] / 128;

  // only layer 2 is live
  const float* Wq2 = Wq + 2 * 128 * 128;
  const float* bq2 = bq + 2 * 128;
  const float* Wk2 = Wk + 2 * 128 * 128;
  const float* bk2 = bk + 2 * 128;
  const float* Wv2 = Wv + 2 * 128 * 128;
  const float* bv2 = bv + 2 * 128;
  const float* g2 = ln_g + 2 * 128;
  const float* lb2 = ln_b + 2 * 128;

  float* ws = (float*)d_ws;
  float* T = ws;                 // 32768
  float* cfull = T + 32768;      // 128
  float* consts = cfull + 128;   // 16
  unsigned short* Wqb = (unsigned short*)(consts + 16);  // 16384 us each
  unsigned short* Wkb = Wqb + 16384;
  unsigned short* Wvb = Wkb + 16384;
  unsigned short* A3b = Wvb + 16384;
  float* fbase = consts + 16 + 32768;  // after 4*16384 bf16 = 32768 floats
  unsigned short* Qb = (unsigned short*)fbase;  // N*128 bf16
  unsigned short* Kb = Qb + (size_t)N * 128;
  float* S = fbase + (size_t)N * 128;  // N*24 (after Qb+Kb)
  float* eArr = S + (size_t)N * 24;    // E
  float* sArr = eArr + E;              // N

  const int zblk = (N + 127) / 128;
  k_TW<<<640 + zblk, 128, 0, stream>>>(W2, W1, Wq2, Wk2, Wv2, T, Wqb, Wkb,
                                       Wvb, sArr, N);
  k_Ac<<<65, 256, 0, stream>>>(W3, T, W2, b1, b2, b3, g2, lb2, fn_g, fn_b,
                               Wvec, A3b, cfull, consts);

  const int nblk = (N + 63) / 64;
  k_node<<<nblk, 256, 0, stream>>>(x, Wqb, Wkb, Wvb, A3b, bq2, bk2, bv2,
                                   cfull, g2, lb2, fn_g, Wvec, Qb, Kb, S, N);
  const int ablk = (E + 15) / 16;
  k_edge_alpha<<<ablk, 256, 0, stream>>>(ei, Qb, Kb, eArr, sArr, E);
  const int oblk = (E + 255) / 256;
  k_edge_out<<<oblk, 256, 0, stream>>>(ei, eArr, sArr, S, consts, bvec,
                                       (float*)d_out, E);
}